// Round 2
// baseline (1018.515 us; speedup 1.0000x reference)
//
#include <hip/hip_runtime.h>
#include <hip/hip_bf16.h>

// Problem constants
#define Hh 8
#define Bb 1024
#define Ss 7
#define Dd 4096
#define DK 512
#define Mrows (Bb*Ss)      // 7168
#define RS 520             // LDS row stride (floats): col 3 = left halo, data 4..515, col 516 = right halo

typedef float  f32x4  __attribute__((ext_vector_type(4)));
typedef float  f32x2  __attribute__((ext_vector_type(2)));
typedef short  bf16x8 __attribute__((ext_vector_type(8)));

static __device__ __forceinline__ unsigned short f2bf(float f) {
  union { float f; unsigned int u; } v; v.f = f;
  unsigned int u = v.u;
  u += 0x7FFFu + ((u >> 16) & 1u);   // RNE
  return (unsigned short)(u >> 16);
}

static __device__ __forceinline__ void gload_lds16(const void* g, void* l) {
  __builtin_amdgcn_global_load_lds(
      (const __attribute__((address_space(1))) unsigned int*)g,
      (__attribute__((address_space(3))) unsigned int*)l,
      16, 0, 0);
}

// scalar neighbor-head sum: src[b, i, (h-1..h+1)*DK + c]
static __device__ __forceinline__ float sum3s(const float* __restrict__ src, int b, int i, int h, int c) {
  long base = (long)(b * Ss + i) * Dd + h * DK + c;
  float v = src[base];
  if (h > 0) v += src[base - DK];
  if (h < 7) v += src[base + DK];
  return v;
}

// ---------------------------------------------------------------------------
// Kernel 1: per (b,h): neighbor-head sum -> conv -> 7x7 attention -> bf16 A rows
// Region-split LDS: K region in bufA, Q then V region in bufB (29 KB total)
// ---------------------------------------------------------------------------
__global__ __launch_bounds__(256, 5) void attn_kernel(
    const float* __restrict__ qg, const float* __restrict__ kg, const float* __restrict__ vg,
    const float* __restrict__ cw, const float* __restrict__ cb,
    unsigned short* __restrict__ Abf)
{
  __shared__ float bufA[Ss][RS];      // K region -> k2
  __shared__ float bufB[Ss][RS];      // Q region -> q2, then V region
  __shared__ float cw4[49][4];        // cw4[o*7+i][j], padded for b128 broadcast
  __shared__ float cb_s[7];
  __shared__ float scores_s[49];
  __shared__ float pmat[7][7];

  const int t    = threadIdx.x;
  const int bh   = blockIdx.x;
  const int b    = bh >> 3, h = bh & 7;
  const int lane = t & 63, wave = t >> 6;

  if (t < 147) { int oi = t / 3; cw4[oi][t - oi * 3] = cw[t]; }
  if (t < 7) {
    cb_s[t] = cb[t];
    bufA[t][3]   = 0.f;                       // K left halo (global pad)
    bufA[t][516] = sum3s(vg, b, t, h, 0);     // K right halo = V col 0
    bufB[t][3]   = sum3s(vg, b, t, h, 511);   // Q left halo = V col 511
    bufB[t][516] = 0.f;                       // Q right halo (global pad)
  }

  // ---- stage K region (bufA) and Q region (bufB): 1792 float4 slots ----
  #pragma unroll
  for (int j = 0; j < 7; ++j) {
    int slot = j * 256 + t;
    int isK  = slot < 896;
    int s2   = isK ? slot : slot - 896;
    int i    = s2 >> 7, c4 = (s2 & 127) << 2;
    const float* src = isK ? kg : qg;
    float* dst = isK ? &bufA[i][4 + c4] : &bufB[i][4 + c4];
    long base = (long)(b * Ss + i) * Dd + h * DK + c4;
    float4 v = *(const float4*)(src + base);
    if (h > 0) { float4 a = *(const float4*)(src + base - DK); v.x+=a.x; v.y+=a.y; v.z+=a.z; v.w+=a.w; }
    if (h < 7) { float4 a = *(const float4*)(src + base + DK); v.x+=a.x; v.y+=a.y; v.z+=a.z; v.w+=a.w; }
    *(float4*)dst = v;
  }
  __syncthreads();

  // ---- conv K and Q regions: thread owns widths w2, w2+1 for all 7 out-channels ----
  const int w2 = 2 * t;
  float ok0[7], ok1[7], oq0[7], oq1[7];
  #pragma unroll
  for (int o = 0; o < 7; ++o) { float c0 = cb_s[o]; ok0[o]=c0; ok1[o]=c0; oq0[o]=c0; oq1[o]=c0; }
  #pragma unroll
  for (int i = 0; i < 7; ++i) {
    float a0 = bufA[i][3+w2], a1 = bufA[i][4+w2], a2 = bufA[i][5+w2], a3 = bufA[i][6+w2];
    float q0 = bufB[i][3+w2], q1 = bufB[i][4+w2], q2 = bufB[i][5+w2], q3 = bufB[i][6+w2];
    #pragma unroll
    for (int o = 0; o < 7; ++o) {
      f32x4 wv = *(const f32x4*)&cw4[o*7+i][0];
      ok0[o] += wv[0]*a0 + wv[1]*a1 + wv[2]*a2;
      ok1[o] += wv[0]*a1 + wv[1]*a2 + wv[2]*a3;
      oq0[o] += wv[0]*q0 + wv[1]*q1 + wv[2]*q2;
      oq1[o] += wv[0]*q1 + wv[1]*q2 + wv[2]*q3;
    }
  }
  __syncthreads();
  #pragma unroll
  for (int o = 0; o < 7; ++o) {
    *(f32x2*)&bufA[o][4 + w2] = (f32x2){ok0[o], ok1[o]};   // k2
    *(f32x2*)&bufB[o][4 + w2] = (f32x2){oq0[o], oq1[o]};   // q2
  }
  __syncthreads();

  // ---- scores: q2 . k2 / sqrt(512); lane-consecutive f32x4 reads (conflict-free) ----
  for (int p = wave; p < 49; p += 4) {
    int qq = p / 7, kk = p - qq * 7;
    f32x4 x0 = *(const f32x4*)&bufB[qq][4 + lane * 4];
    f32x4 x1 = *(const f32x4*)&bufB[qq][4 + 256 + lane * 4];
    f32x4 y0 = *(const f32x4*)&bufA[kk][4 + lane * 4];
    f32x4 y1 = *(const f32x4*)&bufA[kk][4 + 256 + lane * 4];
    float part = x0[0]*y0[0] + x0[1]*y0[1] + x0[2]*y0[2] + x0[3]*y0[3]
               + x1[0]*y1[0] + x1[1]*y1[1] + x1[2]*y1[2] + x1[3]*y1[3];
    #pragma unroll
    for (int off = 32; off; off >>= 1) part += __shfl_xor(part, off);
    if (lane == 0) scores_s[p] = part * 0.044194173824159216f;
  }
  __syncthreads();

  // ---- softmax (t<7) + stage V region into bufB (q2 dead now) ----
  if (t < 7) {
    float row[7], m = -1e30f;
    #pragma unroll
    for (int k = 0; k < 7; ++k) { row[k] = scores_s[t * 7 + k]; m = fmaxf(m, row[k]); }
    float s = 0.f;
    #pragma unroll
    for (int k = 0; k < 7; ++k) { row[k] = __expf(row[k] - m); s += row[k]; }
    float inv = 1.0f / s;
    #pragma unroll
    for (int k = 0; k < 7; ++k) pmat[t][k] = row[k] * inv;
    bufB[t][3]   = sum3s(kg, b, t, h, 511);   // V left halo = K col 511
    bufB[t][516] = sum3s(qg, b, t, h, 0);     // V right halo = Q col 0
  }
  #pragma unroll
  for (int j = 0; j < 4; ++j) {
    int slot = j * 256 + t;
    if (slot < 896) {
      int i = slot >> 7, c4 = (slot & 127) << 2;
      long base = (long)(b * Ss + i) * Dd + h * DK + c4;
      float4 v = *(const float4*)(vg + base);
      if (h > 0) { float4 a = *(const float4*)(vg + base - DK); v.x+=a.x; v.y+=a.y; v.z+=a.z; v.w+=a.w; }
      if (h < 7) { float4 a = *(const float4*)(vg + base + DK); v.x+=a.x; v.y+=a.y; v.z+=a.z; v.w+=a.w; }
      *(float4*)&bufB[i][4 + c4] = v;
    }
  }
  __syncthreads();

  // ---- conv V (in regs) + PV directly from regs: thread owns v2[*][w2..w2+1] ----
  float ov0[7], ov1[7];
  #pragma unroll
  for (int o = 0; o < 7; ++o) { float c0 = cb_s[o]; ov0[o] = c0; ov1[o] = c0; }
  #pragma unroll
  for (int i = 0; i < 7; ++i) {
    float v0 = bufB[i][3+w2], v1 = bufB[i][4+w2], v2 = bufB[i][5+w2], v3 = bufB[i][6+w2];
    #pragma unroll
    for (int o = 0; o < 7; ++o) {
      f32x4 wv = *(const f32x4*)&cw4[o*7+i][0];
      ov0[o] += wv[0]*v0 + wv[1]*v1 + wv[2]*v2;
      ov1[o] += wv[0]*v1 + wv[1]*v2 + wv[2]*v3;
    }
  }
  #pragma unroll
  for (int qq = 0; qq < 7; ++qq) {
    float a0 = 0.f, a1 = 0.f;
    #pragma unroll
    for (int k = 0; k < 7; ++k) { float pk = pmat[qq][k]; a0 += pk * ov0[k]; a1 += pk * ov1[k]; }
    unsigned int packed = ((unsigned int)f2bf(a1) << 16) | (unsigned int)f2bf(a0);
    *(unsigned int*)&Abf[(long)(b * Ss + qq) * Dd + h * DK + w2] = packed;
  }
}

// ---------------------------------------------------------------------------
// Kernel 3: cast w_out (fp32, N x K row-major) -> bf16
// ---------------------------------------------------------------------------
__global__ __launch_bounds__(256) void castw(const float* __restrict__ w, unsigned short* __restrict__ o)
{
  const int total = (Dd * Dd) / 4;
  for (int s = blockIdx.x * 256 + threadIdx.x; s < total; s += gridDim.x * 256) {
    float4 f = *(const float4*)(w + (long)s * 4);
    ushort4 u;
    u.x = f2bf(f.x); u.y = f2bf(f.y); u.z = f2bf(f.z); u.w = f2bf(f.w);
    *(ushort4*)(o + (long)s * 4) = u;
  }
}

// ---------------------------------------------------------------------------
// Kernel 2: bf16 GEMM  C[m][n] = sum_k A[m][k] * W[n][k] + bias[n]
// m97 structure + XCD-aware swizzle (grid 1792 = 8 XCD * 224)
// ---------------------------------------------------------------------------
#define BM 128
#define BN 128
#define BK 32
#define NTILES (Dd / BN)          // 32
#define MTILES (Mrows / BM)       // 56

__global__ __launch_bounds__(256) void gemm_bt(
    const unsigned short* __restrict__ A, const unsigned short* __restrict__ Bt,
    const float* __restrict__ bias, float* __restrict__ C)
{
  __shared__ unsigned short As[BM * BK];
  __shared__ unsigned short Bs[BN * BK];

  const int wg = blockIdx.x;
  const int sw = (wg & 7) * (NTILES * MTILES / 8) + (wg >> 3);   // XCD swizzle (1792 % 8 == 0)
  const int m0 = (sw >> 5) * BM;
  const int n0 = (sw & 31) * BN;

  const int t    = threadIdx.x;
  const int wave = t >> 6, lane = t & 63;
  const int wm   = (wave >> 1) * 64, wn = (wave & 1) * 64;
  const int lr   = lane & 15, lk = (lane >> 4) * 8;

  const int srow = t >> 2;
  const int scol = (t & 3) * 8;

  f32x4 acc[4][4] = {};

  for (int kt = 0; kt < Dd / BK; ++kt) {
    const int k0 = kt * BK;
    #pragma unroll
    for (int j = 0; j < 2; ++j) {
      const int row = j * 64 + srow;
      gload_lds16(A  + (long)(m0 + row) * Dd + k0 + scol, &As[row * BK + scol]);
      gload_lds16(Bt + (long)(n0 + row) * Dd + k0 + scol, &Bs[row * BK + scol]);
    }
    __syncthreads();

    bf16x8 af[4], bfr[4];
    #pragma unroll
    for (int mi = 0; mi < 4; ++mi) af[mi]  = *(const bf16x8*)&As[(wm + mi * 16 + lr) * BK + lk];
    #pragma unroll
    for (int ni = 0; ni < 4; ++ni) bfr[ni] = *(const bf16x8*)&Bs[(wn + ni * 16 + lr) * BK + lk];
    #pragma unroll
    for (int mi = 0; mi < 4; ++mi)
      #pragma unroll
      for (int ni = 0; ni < 4; ++ni)
        acc[mi][ni] = __builtin_amdgcn_mfma_f32_16x16x32_bf16(af[mi], bfr[ni], acc[mi][ni], 0, 0, 0);
    __syncthreads();
  }

  #pragma unroll
  for (int ni = 0; ni < 4; ++ni) {
    const int col = n0 + wn + ni * 16 + lr;
    const float bi = bias[col];
    #pragma unroll
    for (int mi = 0; mi < 4; ++mi) {
      const int rbase = m0 + wm + mi * 16 + (lane >> 4) * 4;
      #pragma unroll
      for (int r = 0; r < 4; ++r)
        C[(long)(rbase + r) * Dd + col] = acc[mi][ni][r] + bi;
    }
  }
}

// ---------------------------------------------------------------------------
extern "C" void kernel_launch(void* const* d_in, const int* in_sizes, int n_in,
                              void* d_out, int out_size, void* d_ws, size_t ws_size,
                              hipStream_t stream) {
  const float* qg = (const float*)d_in[0];
  const float* kg = (const float*)d_in[1];
  const float* vg = (const float*)d_in[2];
  const float* cw = (const float*)d_in[3];
  const float* cb = (const float*)d_in[4];
  const float* wo = (const float*)d_in[5];
  const float* bo = (const float*)d_in[6];
  float* out = (float*)d_out;

  unsigned short* Abf = (unsigned short*)d_ws;                 // 7168*4096 bf16
  unsigned short* Wbf = Abf + (size_t)Mrows * Dd;              // 4096*4096 bf16

  hipLaunchKernelGGL(castw,       dim3(2048),    dim3(256), 0, stream, wo, Wbf);
  hipLaunchKernelGGL(attn_kernel, dim3(Bb * Hh), dim3(256), 0, stream, qg, kg, vg, cw, cb, Abf);
  hipLaunchKernelGGL(gemm_bt,     dim3(NTILES * MTILES), dim3(256), 0, stream, Abf, Wbf, bo, out);
}

// Round 3
// 822.540 us; speedup vs baseline: 1.2383x; 1.2383x over previous
//
#include <hip/hip_runtime.h>
#include <hip/hip_bf16.h>

// Problem constants
#define Hh 8
#define Bb 1024
#define Ss 7
#define Dd 4096
#define DK 512
#define Mrows (Bb*Ss)      // 7168
#define RS 520             // LDS row stride (floats): col 3 = left halo, data 4..515, col 516 = right halo

typedef float  f32x4  __attribute__((ext_vector_type(4)));
typedef float  f32x2  __attribute__((ext_vector_type(2)));
typedef short  bf16x8 __attribute__((ext_vector_type(8)));

static __device__ __forceinline__ unsigned short f2bf(float f) {
  union { float f; unsigned int u; } v; v.f = f;
  unsigned int u = v.u;
  u += 0x7FFFu + ((u >> 16) & 1u);   // RNE
  return (unsigned short)(u >> 16);
}

static __device__ __forceinline__ void gload_lds16(const void* g, void* l) {
  __builtin_amdgcn_global_load_lds(
      (const __attribute__((address_space(1))) unsigned int*)g,
      (__attribute__((address_space(3))) unsigned int*)l,
      16, 0, 0);
}

// scalar neighbor-head sum: src[b, i, (h-1..h+1)*DK + c]
static __device__ __forceinline__ float sum3s(const float* __restrict__ src, int b, int i, int h, int c) {
  long base = (long)(b * Ss + i) * Dd + h * DK + c;
  float v = src[base];
  if (h > 0) v += src[base - DK];
  if (h < 7) v += src[base + DK];
  return v;
}

// ---------------------------------------------------------------------------
// Kernel 1: per (b,h): neighbor-head sum -> conv -> 7x7 attention -> bf16 A rows
// Conv split into K-pass / Q-pass (max 14 live accs -> no scratch spill).
// XCD-chunked swizzle: all 8 heads of a batch on one XCD (neighbor reads L2-hit).
// ---------------------------------------------------------------------------
__global__ __launch_bounds__(256) void attn_kernel(
    const float* __restrict__ qg, const float* __restrict__ kg, const float* __restrict__ vg,
    const float* __restrict__ cw, const float* __restrict__ cb,
    unsigned short* __restrict__ Abf)
{
  __shared__ float bufA[Ss][RS];      // K region -> k2
  __shared__ float bufB[Ss][RS];      // Q region -> q2, then V region
  __shared__ float cw4[49][4];        // cw4[o*7+i][j], padded for b128 broadcast
  __shared__ float cb_s[7];
  __shared__ float scores_s[49];
  __shared__ float pmat[7][7];

  const int t    = threadIdx.x;
  const int g    = blockIdx.x;
  const int bh   = (g & 7) * (Bb * Hh / 8) + (g >> 3);   // XCD chunking (8192 % 8 == 0)
  const int b    = bh >> 3, h = bh & 7;
  const int lane = t & 63, wave = t >> 6;

  if (t < 147) { int oi = t / 3; cw4[oi][t - oi * 3] = cw[t]; }
  if (t < 7) {
    cb_s[t] = cb[t];
    bufA[t][3]   = 0.f;                       // K left halo (global pad)
    bufA[t][516] = sum3s(vg, b, t, h, 0);     // K right halo = V col 0
    bufB[t][3]   = sum3s(vg, b, t, h, 511);   // Q left halo = V col 511
    bufB[t][516] = 0.f;                       // Q right halo (global pad)
  }

  // ---- stage K region (bufA) and Q region (bufB): 1792 float4 slots ----
  #pragma unroll
  for (int j = 0; j < 7; ++j) {
    int slot = j * 256 + t;
    int isK  = slot < 896;
    int s2   = isK ? slot : slot - 896;
    int i    = s2 >> 7, c4 = (s2 & 127) << 2;
    const float* src = isK ? kg : qg;
    float* dst = isK ? &bufA[i][4 + c4] : &bufB[i][4 + c4];
    long base = (long)(b * Ss + i) * Dd + h * DK + c4;
    float4 v = *(const float4*)(src + base);
    if (h > 0) { float4 a = *(const float4*)(src + base - DK); v.x+=a.x; v.y+=a.y; v.z+=a.z; v.w+=a.w; }
    if (h < 7) { float4 a = *(const float4*)(src + base + DK); v.x+=a.x; v.y+=a.y; v.z+=a.z; v.w+=a.w; }
    *(float4*)dst = v;
  }
  __syncthreads();

  const int w2 = 2 * t;

  // ---- conv pass 1: K region (14 live accumulators) ----
  float c0a[7], c1a[7];
  #pragma unroll
  for (int o = 0; o < 7; ++o) { c0a[o] = cb_s[o]; c1a[o] = cb_s[o]; }
  #pragma unroll
  for (int i = 0; i < 7; ++i) {
    float a0 = bufA[i][3+w2], a1 = bufA[i][4+w2], a2 = bufA[i][5+w2], a3 = bufA[i][6+w2];
    #pragma unroll
    for (int o = 0; o < 7; ++o) {
      f32x4 wv = *(const f32x4*)&cw4[o*7+i][0];
      c0a[o] += wv[0]*a0 + wv[1]*a1 + wv[2]*a2;
      c1a[o] += wv[0]*a1 + wv[1]*a2 + wv[2]*a3;
    }
  }
  __syncthreads();                                       // all bufA reads done
  #pragma unroll
  for (int o = 0; o < 7; ++o)
    *(f32x2*)&bufA[o][4 + w2] = (f32x2){c0a[o], c1a[o]}; // k2 -> bufA

  // ---- conv pass 2: Q region ----
  #pragma unroll
  for (int o = 0; o < 7; ++o) { c0a[o] = cb_s[o]; c1a[o] = cb_s[o]; }
  #pragma unroll
  for (int i = 0; i < 7; ++i) {
    float a0 = bufB[i][3+w2], a1 = bufB[i][4+w2], a2 = bufB[i][5+w2], a3 = bufB[i][6+w2];
    #pragma unroll
    for (int o = 0; o < 7; ++o) {
      f32x4 wv = *(const f32x4*)&cw4[o*7+i][0];
      c0a[o] += wv[0]*a0 + wv[1]*a1 + wv[2]*a2;
      c1a[o] += wv[0]*a1 + wv[1]*a2 + wv[2]*a3;
    }
  }
  __syncthreads();                                       // all bufB reads + k2 writes done
  #pragma unroll
  for (int o = 0; o < 7; ++o)
    *(f32x2*)&bufB[o][4 + w2] = (f32x2){c0a[o], c1a[o]}; // q2 -> bufB
  __syncthreads();

  // ---- scores: q2 . k2 / sqrt(512); lane-consecutive f32x4 reads (conflict-free) ----
  for (int p = wave; p < 49; p += 4) {
    int qq = p / 7, kk = p - qq * 7;
    f32x4 x0 = *(const f32x4*)&bufB[qq][4 + lane * 4];
    f32x4 x1 = *(const f32x4*)&bufB[qq][4 + 256 + lane * 4];
    f32x4 y0 = *(const f32x4*)&bufA[kk][4 + lane * 4];
    f32x4 y1 = *(const f32x4*)&bufA[kk][4 + 256 + lane * 4];
    float part = x0[0]*y0[0] + x0[1]*y0[1] + x0[2]*y0[2] + x0[3]*y0[3]
               + x1[0]*y1[0] + x1[1]*y1[1] + x1[2]*y1[2] + x1[3]*y1[3];
    #pragma unroll
    for (int off = 32; off; off >>= 1) part += __shfl_xor(part, off);
    if (lane == 0) scores_s[p] = part * 0.044194173824159216f;
  }
  __syncthreads();

  // ---- softmax (t<7) + stage V region into bufB (q2 dead now) ----
  if (t < 7) {
    float row[7], m = -1e30f;
    #pragma unroll
    for (int k = 0; k < 7; ++k) { row[k] = scores_s[t * 7 + k]; m = fmaxf(m, row[k]); }
    float s = 0.f;
    #pragma unroll
    for (int k = 0; k < 7; ++k) { row[k] = __expf(row[k] - m); s += row[k]; }
    float inv = 1.0f / s;
    #pragma unroll
    for (int k = 0; k < 7; ++k) pmat[t][k] = row[k] * inv;
    bufB[t][3]   = sum3s(kg, b, t, h, 511);   // V left halo = K col 511
    bufB[t][516] = sum3s(qg, b, t, h, 0);     // V right halo = Q col 0
  }
  #pragma unroll
  for (int j = 0; j < 4; ++j) {
    int slot = j * 256 + t;
    if (slot < 896) {
      int i = slot >> 7, c4 = (slot & 127) << 2;
      long base = (long)(b * Ss + i) * Dd + h * DK + c4;
      float4 v = *(const float4*)(vg + base);
      if (h > 0) { float4 a = *(const float4*)(vg + base - DK); v.x+=a.x; v.y+=a.y; v.z+=a.z; v.w+=a.w; }
      if (h < 7) { float4 a = *(const float4*)(vg + base + DK); v.x+=a.x; v.y+=a.y; v.z+=a.z; v.w+=a.w; }
      *(float4*)&bufB[i][4 + c4] = v;
    }
  }
  __syncthreads();

  // ---- conv V (14 accs) + PV directly from regs: thread owns v2[*][w2..w2+1] ----
  float ov0[7], ov1[7];
  #pragma unroll
  for (int o = 0; o < 7; ++o) { ov0[o] = cb_s[o]; ov1[o] = cb_s[o]; }
  #pragma unroll
  for (int i = 0; i < 7; ++i) {
    float v0 = bufB[i][3+w2], v1 = bufB[i][4+w2], v2 = bufB[i][5+w2], v3 = bufB[i][6+w2];
    #pragma unroll
    for (int o = 0; o < 7; ++o) {
      f32x4 wv = *(const f32x4*)&cw4[o*7+i][0];
      ov0[o] += wv[0]*v0 + wv[1]*v1 + wv[2]*v2;
      ov1[o] += wv[0]*v1 + wv[1]*v2 + wv[2]*v3;
    }
  }
  #pragma unroll
  for (int qq = 0; qq < 7; ++qq) {
    float a0 = 0.f, a1 = 0.f;
    #pragma unroll
    for (int k = 0; k < 7; ++k) { float pk = pmat[qq][k]; a0 += pk * ov0[k]; a1 += pk * ov1[k]; }
    unsigned int packed = ((unsigned int)f2bf(a1) << 16) | (unsigned int)f2bf(a0);
    *(unsigned int*)&Abf[(long)(b * Ss + qq) * Dd + h * DK + w2] = packed;
  }
}

// ---------------------------------------------------------------------------
// Kernel 3: cast w_out (fp32, N x K row-major) -> bf16
// ---------------------------------------------------------------------------
__global__ __launch_bounds__(256) void castw(const float* __restrict__ w, unsigned short* __restrict__ o)
{
  const int total = (Dd * Dd) / 4;
  for (int s = blockIdx.x * 256 + threadIdx.x; s < total; s += gridDim.x * 256) {
    float4 f = *(const float4*)(w + (long)s * 4);
    ushort4 u;
    u.x = f2bf(f.x); u.y = f2bf(f.y); u.z = f2bf(f.z); u.w = f2bf(f.w);
    *(ushort4*)(o + (long)s * 4) = u;
  }
}

// ---------------------------------------------------------------------------
// Kernel 2: bf16 GEMM  C[m][n] = sum_k A[m][k] * W[n][k] + bias[n]
// m97 structure: 128x128 tile, BK=32, 4 waves, global_load_lds(16B), 16x16x32 MFMA
// ---------------------------------------------------------------------------
#define BM 128
#define BN 128
#define BK 32

__global__ __launch_bounds__(256) void gemm_bt(
    const unsigned short* __restrict__ A, const unsigned short* __restrict__ Bt,
    const float* __restrict__ bias, float* __restrict__ C)
{
  __shared__ unsigned short As[BM * BK];
  __shared__ unsigned short Bs[BN * BK];

  const int t    = threadIdx.x;
  const int m0   = blockIdx.y * BM;
  const int n0   = blockIdx.x * BN;
  const int wave = t >> 6, lane = t & 63;
  const int wm   = (wave >> 1) * 64, wn = (wave & 1) * 64;
  const int lr   = lane & 15, lk = (lane >> 4) * 8;

  const int srow = t >> 2;
  const int scol = (t & 3) * 8;

  f32x4 acc[4][4] = {};

  for (int kt = 0; kt < Dd / BK; ++kt) {
    const int k0 = kt * BK;
    #pragma unroll
    for (int j = 0; j < 2; ++j) {
      const int row = j * 64 + srow;
      gload_lds16(A  + (long)(m0 + row) * Dd + k0 + scol, &As[row * BK + scol]);
      gload_lds16(Bt + (long)(n0 + row) * Dd + k0 + scol, &Bs[row * BK + scol]);
    }
    __syncthreads();

    bf16x8 af[4], bfr[4];
    #pragma unroll
    for (int mi = 0; mi < 4; ++mi) af[mi]  = *(const bf16x8*)&As[(wm + mi * 16 + lr) * BK + lk];
    #pragma unroll
    for (int ni = 0; ni < 4; ++ni) bfr[ni] = *(const bf16x8*)&Bs[(wn + ni * 16 + lr) * BK + lk];
    #pragma unroll
    for (int mi = 0; mi < 4; ++mi)
      #pragma unroll
      for (int ni = 0; ni < 4; ++ni)
        acc[mi][ni] = __builtin_amdgcn_mfma_f32_16x16x32_bf16(af[mi], bfr[ni], acc[mi][ni], 0, 0, 0);
    __syncthreads();
  }

  #pragma unroll
  for (int ni = 0; ni < 4; ++ni) {
    const int col = n0 + wn + ni * 16 + lr;
    const float bi = bias[col];
    #pragma unroll
    for (int mi = 0; mi < 4; ++mi) {
      const int rbase = m0 + wm + mi * 16 + (lane >> 4) * 4;
      #pragma unroll
      for (int r = 0; r < 4; ++r)
        C[(long)(rbase + r) * Dd + col] = acc[mi][ni][r] + bi;
    }
  }
}

// ---------------------------------------------------------------------------
extern "C" void kernel_launch(void* const* d_in, const int* in_sizes, int n_in,
                              void* d_out, int out_size, void* d_ws, size_t ws_size,
                              hipStream_t stream) {
  const float* qg = (const float*)d_in[0];
  const float* kg = (const float*)d_in[1];
  const float* vg = (const float*)d_in[2];
  const float* cw = (const float*)d_in[3];
  const float* cb = (const float*)d_in[4];
  const float* wo = (const float*)d_in[5];
  const float* bo = (const float*)d_in[6];
  float* out = (float*)d_out;

  unsigned short* Abf = (unsigned short*)d_ws;                 // 7168*4096 bf16
  unsigned short* Wbf = Abf + (size_t)Mrows * Dd;              // 4096*4096 bf16

  hipLaunchKernelGGL(castw,       dim3(2048),    dim3(256), 0, stream, wo, Wbf);
  hipLaunchKernelGGL(attn_kernel, dim3(Bb * Hh), dim3(256), 0, stream, qg, kg, vg, cw, cb, Abf);
  hipLaunchKernelGGL(gemm_bt,     dim3(Dd / BN, Mrows / BM), dim3(256), 0, stream, Abf, Wbf, bo, out);
}